// Round 6
// baseline (351.057 us; speedup 1.0000x reference)
//
#include <hip/hip_runtime.h>

#define HDIM 1024
#define BDIM 32
#define LDIM 1024

// ws layout (floats): u1[0:H], u2[H:2H], vbar[2H : 2H+B*H], logits[2H+B*H : +B*L]

typedef float vfloat4 __attribute__((ext_vector_type(4)));

__device__ __forceinline__ float dot4(float4 a, float4 b) {
    return a.x * b.x + a.y * b.y + a.z * b.z + a.w * b.w;
}

__device__ __forceinline__ float4 ntload4(const float4* p) {
    vfloat4 v = __builtin_nontemporal_load((const vfloat4*)p);
    return make_float4(v.x, v.y, v.z, v.w);
}

// u1[h] = sum_o W[o,h]*w1[o]; u2[h] = sum_o W[o,h]*w2[o]. Coalesced row reads.
__global__ __launch_bounds__(256) void k_u12(const float4* __restrict__ W4,
                                             const float* __restrict__ mlp_w,
                                             float* __restrict__ u1,
                                             float* __restrict__ u2) {
    int t  = threadIdx.x;            // float4 index within a row, [0,256)
    int o0 = blockIdx.x * 16;        // 64 blocks x 16 rows
    float4 s1 = make_float4(0.f, 0.f, 0.f, 0.f);
    float4 s2 = make_float4(0.f, 0.f, 0.f, 0.f);
    #pragma unroll 4
    for (int o = o0; o < o0 + 16; ++o) {
        float4 w = W4[o * 256 + t];
        float c1 = mlp_w[o];
        float c2 = mlp_w[HDIM + o];
        s1.x += w.x * c1; s1.y += w.y * c1; s1.z += w.z * c1; s1.w += w.w * c1;
        s2.x += w.x * c2; s2.y += w.y * c2; s2.z += w.z * c2; s2.w += w.w * c2;
    }
    int h = t * 4;
    atomicAdd(&u1[h + 0], s1.x); atomicAdd(&u1[h + 1], s1.y);
    atomicAdd(&u1[h + 2], s1.z); atomicAdd(&u1[h + 3], s1.w);
    atomicAdd(&u2[h + 0], s2.x); atomicAdd(&u2[h + 1], s2.y);
    atomicAdd(&u2[h + 2], s2.z); atomicAdd(&u2[h + 3], s2.w);
}

// logits[row] = relu(q[row]·u1 + k[row]·u2 + b).
// Block owns 8 rows; thread owns float4 slice t of each row. 16 nontemporal
// loads in flight (8 q + 8 k) before any use. Cross-wave LDS combine
// (each wave's shuffle-reduce is a quarter dot).
__global__ __launch_bounds__(256) void k_logits(const float4* __restrict__ q,
                                                const float4* __restrict__ k,
                                                const float4* __restrict__ u1v,
                                                const float4* __restrict__ u2v,
                                                const float* __restrict__ mlp_b,
                                                float* __restrict__ logits) {
    __shared__ float sm[8][4];
    int t = threadIdx.x;
    int lane = t & 63, wave = t >> 6;
    float4 a1 = u1v[t];
    float4 a2 = u2v[t];
    float bias = mlp_b[0];
    long long r0 = (long long)blockIdx.x * 8;    // [0, 32768) step 8
    const float4* qb = q + r0 * 256 + t;
    const float4* kb = k + r0 * 256 + t;
    float4 xq[8], xk[8];
    #pragma unroll
    for (int r = 0; r < 8; ++r) xq[r] = ntload4(qb + r * 256);
    #pragma unroll
    for (int r = 0; r < 8; ++r) xk[r] = ntload4(kb + r * 256);
    float p[8];
    #pragma unroll
    for (int r = 0; r < 8; ++r)
        p[r] = dot4(xq[r], a1) + dot4(xk[r], a2);
    // 8 independent reduce chains, stage-major so they pipeline
    #pragma unroll
    for (int off = 32; off > 0; off >>= 1)
        #pragma unroll
        for (int r = 0; r < 8; ++r)
            p[r] += __shfl_down(p[r], off, 64);
    if (lane == 0) {
        #pragma unroll
        for (int r = 0; r < 8; ++r)
            sm[r][wave] = p[r];
    }
    __syncthreads();
    if (t < 8) {
        float v = sm[t][0] + sm[t][1] + sm[t][2] + sm[t][3] + bias;
        logits[r0 + t] = v > 0.f ? v : 0.f;
    }
}

__global__ __launch_bounds__(256) void k_softmax(const float* __restrict__ logits,
                                                 float* __restrict__ score) {
    __shared__ float sm[4];
    __shared__ float ss[4];
    int b = blockIdx.x;
    int t = threadIdx.x;
    int wave = t >> 6, lane = t & 63;
    float4 v = ((const float4*)(logits + b * LDIM))[t];
    float m = fmaxf(fmaxf(v.x, v.y), fmaxf(v.z, v.w));
    #pragma unroll
    for (int off = 32; off > 0; off >>= 1)
        m = fmaxf(m, __shfl_down(m, off, 64));
    if (lane == 0) sm[wave] = m;
    __syncthreads();
    float M = fmaxf(fmaxf(sm[0], sm[1]), fmaxf(sm[2], sm[3]));
    float4 e;
    e.x = __expf(v.x - M); e.y = __expf(v.y - M);
    e.z = __expf(v.z - M); e.w = __expf(v.w - M);
    float s = e.x + e.y + e.z + e.w;
    #pragma unroll
    for (int off = 32; off > 0; off >>= 1)
        s += __shfl_down(s, off, 64);
    if (lane == 0) ss[wave] = s;
    __syncthreads();
    float inv = 1.f / (ss[0] + ss[1] + ss[2] + ss[3]);
    float4 o;
    o.x = e.x * inv; o.y = e.y * inv; o.z = e.z * inv; o.w = e.w * inv;
    ((float4*)(score + b * LDIM))[t] = o;
}

// vbar[b,h] = sum_l score[b,l] * value[b,l,h].
// Grid 2048: (b, h-chunk of 256 floats, l-slice of 64 rows). Scores staged in
// LDS once (lane-uniform broadcast reads); 16 nontemporal value loads in
// flight per thread; LDS cross-wave reduce; 4 atomics per lane of wave 0.
__global__ __launch_bounds__(256) void k_vbar(const float4* __restrict__ value,
                                              const float* __restrict__ score,
                                              float* __restrict__ vbar) {
    __shared__ float sc_lds[64];
    __shared__ float4 red[3][64];
    int bid = blockIdx.x;
    int b  = bid >> 6;           // [0,32)
    int hc = (bid >> 4) & 3;     // [0,4)
    int ls = bid & 15;           // [0,16) l-slices of 64 rows
    int t = threadIdx.x, lane = t & 63, wave = t >> 6;
    const float4* vb = value + ((long long)(b * LDIM + ls * 64) * 256) + hc * 64 + lane;
    if (t < 64) sc_lds[t] = score[b * LDIM + ls * 64 + t];
    __syncthreads();
    // wave handles l = wave + 4*i, i in [0,16); all 16 loads in flight
    float4 v[16];
    #pragma unroll
    for (int i = 0; i < 16; ++i)
        v[i] = ntload4(vb + (wave + 4 * i) * 256);
    float4 acc = make_float4(0.f, 0.f, 0.f, 0.f);
    #pragma unroll
    for (int i = 0; i < 16; ++i) {
        float s = sc_lds[wave + 4 * i];
        acc.x += s * v[i].x;
        acc.y += s * v[i].y;
        acc.z += s * v[i].z;
        acc.w += s * v[i].w;
    }
    if (wave > 0) red[wave - 1][lane] = acc;
    __syncthreads();
    if (wave == 0) {
        float4 r0 = red[0][lane], r1 = red[1][lane], r2 = red[2][lane];
        acc.x += r0.x + r1.x + r2.x;
        acc.y += r0.y + r1.y + r2.y;
        acc.z += r0.z + r1.z + r2.z;
        acc.w += r0.w + r1.w + r2.w;
        float* dst = vbar + b * HDIM + hc * 256 + lane * 4;
        atomicAdd(dst + 0, acc.x);
        atomicAdd(dst + 1, acc.y);
        atomicAdd(dst + 2, acc.z);
        atomicAdd(dst + 3, acc.w);
    }
}

// result[b,o] = sum_h W[o,h] * vbar[b,h]. One wave per o; b-range split 4-way.
__global__ __launch_bounds__(256) void k_result(const float4* __restrict__ W4,
                                                const float4* __restrict__ vbar4,
                                                float* __restrict__ result) {
    int t = threadIdx.x;
    int lane = t & 63, wave = t >> 6;
    int o  = (blockIdx.x & 255) * 4 + wave;   // [0,1024)
    int b0 = (blockIdx.x >> 8) * 8;           // {0,8,16,24}
    float4 w[4];
    #pragma unroll
    for (int i = 0; i < 4; ++i)
        w[i] = W4[o * 256 + lane + 64 * i];
    for (int b = b0; b < b0 + 8; b += 2) {
        float acc0 = 0.f, acc1 = 0.f;
        #pragma unroll
        for (int i = 0; i < 4; ++i) {
            float4 v0 = vbar4[b * 256 + lane + 64 * i];
            acc0 += v0.x * w[i].x + v0.y * w[i].y + v0.z * w[i].z + v0.w * w[i].w;
            float4 v1 = vbar4[(b + 1) * 256 + lane + 64 * i];
            acc1 += v1.x * w[i].x + v1.y * w[i].y + v1.z * w[i].z + v1.w * w[i].w;
        }
        #pragma unroll
        for (int off = 32; off > 0; off >>= 1) {
            acc0 += __shfl_down(acc0, off, 64);
            acc1 += __shfl_down(acc1, off, 64);
        }
        if (lane == 0) {
            result[b * HDIM + o]       = acc0;
            result[(b + 1) * HDIM + o] = acc1;
        }
    }
}

extern "C" void kernel_launch(void* const* d_in, const int* in_sizes, int n_in,
                              void* d_out, int out_size, void* d_ws, size_t ws_size,
                              hipStream_t stream) {
    const float* query = (const float*)d_in[0];
    const float* key   = (const float*)d_in[1];
    const float* value = (const float*)d_in[2];
    const float* W     = (const float*)d_in[3];
    const float* mlp_w = (const float*)d_in[4];
    const float* mlp_b = (const float*)d_in[5];

    float* out    = (float*)d_out;
    float* result = out;                 // B*H
    float* score  = out + BDIM * LDIM;   // B*L

    float* u1     = (float*)d_ws;
    float* u2     = u1 + HDIM;
    float* vbar   = u2 + HDIM;           // B*H
    float* logits = vbar + BDIM * HDIM;  // B*L

    hipMemsetAsync(d_ws, 0, (size_t)(2 * HDIM + BDIM * HDIM) * sizeof(float), stream);

    k_u12<<<64, 256, 0, stream>>>((const float4*)W, mlp_w, u1, u2);
    k_logits<<<4096, 256, 0, stream>>>((const float4*)query, (const float4*)key,
                                       (const float4*)u1, (const float4*)u2, mlp_b, logits);
    k_softmax<<<BDIM, 256, 0, stream>>>(logits, score);
    k_vbar<<<2048, 256, 0, stream>>>((const float4*)value, score, vbar);
    k_result<<<1024, 256, 0, stream>>>((const float4*)W, (const float4*)vbar, out);
}